// Round 9
// baseline (776.303 us; speedup 1.0000x reference)
//
#include <hip/hip_runtime.h>
#include <hip/hip_fp16.h>

#define T_SEQ 2048
#define HID   50
#define KP    64      // k: 0..49 = h, 50..62 = onehot, 63 = bias
#define MB    8       // batch rows per block (16 A-rows = 8 real x 2 dup)
#define NBLK  256     // 2048 / MB -> 1 block/CU
#define NTHR  256     // 4 waves -> 1 wave/SIMD (chain-minimal, no lockstep partner)
#define HSTR  80      // ushorts per h row (160 B); slots 64..79 = pad-unit dump zone
#define BUFB  (MB*HSTR)   // 640 ushorts per buffer

#define NLOG2E  1.4426950408889634f   // gates scaled by -log2e (g-gate by -2log2e) in B
#define N2LOG2E 2.8853900817779268f

typedef __attribute__((ext_vector_type(8))) _Float16 half8;
typedef __attribute__((ext_vector_type(4))) float    f32x4;

__device__ __forceinline__ ushort f16b(float f){ return __half_as_ushort(__float2half(f)); }
__device__ __forceinline__ float rcp_(float x){ return __builtin_amdgcn_rcpf(x); }
__device__ __forceinline__ float ex2_(float x){ return __builtin_amdgcn_exp2f(x); }

// Bm[256 cols][64 k] f16.  col = w*64 + g*16 + c16 encodes unit u = w*16+c16, gate g
// (g: 0=i,1=f,2=g,3=o).  Row r = g*50+u.  Entries pre-scaled by -log2e (g-gate by
// -2log2e) so the MFMA emits gates in exp2 domain:
//   k<50: s*W_hh[r][k];  k in 50..62: s*embed[k-50]·W_ih[r];  k==63: s*(b_ih+b_hh)[r].
__global__ void build_B(const float* __restrict__ embed, const float* __restrict__ Wih,
                        const float* __restrict__ Whh, const float* __restrict__ bih,
                        const float* __restrict__ bhh, ushort* __restrict__ Bm) {
    int idx = blockIdx.x * blockDim.x + threadIdx.x;
    if (idx >= 256 * KP) return;
    int col = idx >> 6, k = idx & 63;
    int wq = col >> 6, g = (col >> 4) & 3, cc = col & 15;
    int u = wq * 16 + cc;
    ushort v = 0;
    if (u < HID) {
        int r = g * HID + u;
        float s = (g == 2) ? -N2LOG2E : -NLOG2E;
        if (k < HID) {
            v = f16b(s * Whh[r * HID + k]);
        } else if (k < 63) {
            float t = 0.f;
            for (int e = 0; e < HID; ++e)
                t = fmaf(embed[(k - 50) * HID + e], Wih[r * HID + e], t);
            v = f16b(s * t);
        } else {
            v = f16b(s * (bih[r] + bhh[r]));
        }
    }
    Bm[idx] = v;
}

// 4 waves, MB=8, 1 block/CU, 1 wave/SIMD. Wave w owns all 4 gate-tiles of units
// 16w+c16; A rows = h[m>>1] (dup x2) puts rows 2q / 2q+1 at accumulator regs [0]/[2]
// -> all 4 gates of both rows lane-local: zero dpp, zero selects, 2 acts/lane.
// Unchained MFMA pairs; branchless pad writes to dump zone; scalar token streams.
__global__ __launch_bounds__(NTHR, 1) void lstm4w(
    const int*    __restrict__ x,
    const ushort* __restrict__ Bm,
    const float*  __restrict__ W1,
    const float*  __restrict__ b1,
    const float*  __restrict__ W2,
    const float*  __restrict__ b2,
    float*        __restrict__ out)
{
    const int t    = threadIdx.x;
    const int w    = t >> 6;          // wave 0..3
    const int l    = t & 63;
    const int q    = l >> 4;
    const int c16  = l & 15;
    const int u    = 16 * w + c16;                  // unit handled by this lane
    const int upos = (u < HID) ? u : (64 + u - HID); // pad units -> dump slots 64..77
    const int wu   = __builtin_amdgcn_readfirstlane(w);

    __shared__ __align__(16) ushort hbuf[2 * BUFB];   // 2560 B, double-buffered
    __shared__ float zb[HID * MB];                    // 1600 B

    // B fragments: wave w owns tiles g=0..3 (gates i,f,g,o) of its 16 units
    half8 bf[4][2];
    {
        const ushort* bp = Bm + (w * 64 + c16) * KP + q * 8;
        #pragma unroll
        for (int g = 0; g < 4; ++g) {
            bf[g][0] = *(const half8*)(bp + g * 16 * KP);
            bf[g][1] = *(const half8*)(bp + g * 16 * KP + 32);
        }
    }
    #pragma unroll
    for (int g = 0; g < 4; ++g)
        asm volatile("" : "+v"(bf[g][0]), "+v"(bf[g][1]));

    for (int i = t; i < 2 * BUFB; i += NTHR) hbuf[i] = 0;

    const int row0 = blockIdx.x * MB;
    __syncthreads();
    if (t < MB) {                                   // per-row init: bias + onehot 0/1
        int tk0 = x[(long)(row0 + t) * T_SEQ + 0];
        int tk1 = x[(long)(row0 + t) * T_SEQ + 1];
        hbuf[0 * BUFB + t * HSTR + 63] = 0x3C00;
        hbuf[1 * BUFB + t * HSTR + 63] = 0x3C00;
        hbuf[0 * BUFB + t * HSTR + 50 + tk0] = 0x3C00;
        hbuf[1 * BUFB + t * HSTR + 50 + tk1] = 0x3C00;
    }
    __syncthreads();

    // wave-uniform token streams: wave w maintains rows w and 4+w (both scalar)
    const int* xA = x + (long)(row0 + wu) * T_SEQ;
    const int* xB = x + (long)(row0 + 4 + wu) * T_SEQ;
    int tA0 = xA[1], tA1 = xA[0], tA2 = xA[1];      // clear(t-1)/set(t+1) window
    int tB0 = xB[1], tB1 = xB[0], tB2 = xB[1];

    // A row m = h[m>>1]: lane pairs broadcast; 2-way banks = free
    const ushort* ar  = hbuf + (c16 >> 1) * HSTR + q * 8;
    ushort*       wr_ = hbuf + (2 * q) * HSTR + upos;   // rows 2q / 2q+1 (+HSTR)

    float cs0 = 0.f, cs1 = 0.f;        // cs = -2*log2e * c  (pre-scaled domain)

#define MFMA_(A,B,C) __builtin_amdgcn_mfma_f32_16x16x32_f16((A),(B),(C),0,0,0)
#define ACT(GI,GF,GG,GO,CS,HH) do {                                               \
        float pi = ex2_(GI);                                                      \
        float pf = ex2_(GF);                                                      \
        float qg = ex2_(GG);                                                      \
        float Df = 1.f + pf;                                                      \
        float D2 = (1.f + pi) * (1.f + qg);                                       \
        float ivA = rcp_(Df * D2);                                                \
        float fv  = ivA * D2;                                                     \
        float igs = ivA * Df * fmaf(N2LOG2E, qg, -N2LOG2E);                       \
        CS = fmaf(fv, CS, igs);                                                   \
        float po = ex2_(GO);                                                      \
        float qc = ex2_(fminf(CS, 30.f));                                         \
        float ivB = rcp_((1.f + po) * (1.f + qc));                                \
        HH = ivB * (1.f - qc);                                                    \
    } while (0)

#define STEP(P) do {                                                              \
        half8 a0 = *(const half8*)(ar + (P) * BUFB);     /* chain head first */   \
        half8 a1 = *(const half8*)(ar + (P) * BUFB + 32);                         \
        int it = step + 2 + (P); if (it > T_SEQ - 1) it = T_SEQ - 1;              \
        int tnA = xA[it];                                /* scalar prefetch */    \
        int tnB = xB[it];                                                         \
        const f32x4 zz = {0.f, 0.f, 0.f, 0.f};                                    \
        f32x4 zA0 = MFMA_(a0, bf[0][0], zz);   /* 8 independent MFMAs */          \
        f32x4 zB0 = MFMA_(a1, bf[0][1], zz);                                      \
        f32x4 zA1 = MFMA_(a0, bf[1][0], zz);                                      \
        f32x4 zB1 = MFMA_(a1, bf[1][1], zz);                                      \
        f32x4 zA2 = MFMA_(a0, bf[2][0], zz);                                      \
        f32x4 zB2 = MFMA_(a1, bf[2][1], zz);                                      \
        f32x4 zA3 = MFMA_(a0, bf[3][0], zz);                                      \
        f32x4 zB3 = MFMA_(a1, bf[3][1], zz);                                      \
        float gi0 = zA0[0] + zB0[0], gi1 = zA0[2] + zB0[2];                       \
        float gf0 = zA1[0] + zB1[0], gf1 = zA1[2] + zB1[2];                       \
        float gg0 = zA2[0] + zB2[0], gg1 = zA2[2] + zB2[2];                       \
        float go0 = zA3[0] + zB3[0], go1 = zA3[2] + zB3[2];                       \
        float h0, h1;                                                             \
        ACT(gi0, gf0, gg0, go0, cs0, h0);      /* row 2q   */                     \
        ACT(gi1, gf1, gg1, go1, cs1, h1);      /* row 2q+1 */                     \
        wr_[(1 - (P)) * BUFB]        = f16b(h0);                                  \
        wr_[(1 - (P)) * BUFB + HSTR] = f16b(h1);                                  \
        if (l == 0) {                          /* token windows, rows wu & 4+wu */\
            ushort* hb = hbuf + (1 - (P)) * BUFB;                                 \
            hb[wu * HSTR + 50 + tA0] = 0;                                         \
            hb[wu * HSTR + 50 + tA2] = 0x3C00;                                    \
            hb[(4 + wu) * HSTR + 50 + tB0] = 0;                                   \
            hb[(4 + wu) * HSTR + 50 + tB2] = 0x3C00;                              \
        }                                                                         \
        tA0 = tA1; tA1 = tA2; tA2 = tnA;                                          \
        tB0 = tB1; tB1 = tB2; tB2 = tnB;                                          \
        __syncthreads();                                                          \
    } while (0)

    #pragma unroll 1
    for (int step = 0; step < T_SEQ; step += 2) {
        STEP(0);
        STEP(1);
    }
#undef STEP
#undef ACT
#undef MFMA_

    // Epilogue MLP: final h in buffer 0 (last step wrote it), already synced.
    for (int idx = t; idx < MB * HID; idx += NTHR) {
        int m = idx & 7, uu = idx >> 3;
        float a = b1[uu];
        const ushort* hr = hbuf + m * HSTR;
        #pragma unroll 10
        for (int k = 0; k < HID; ++k)
            a = fmaf(W1[uu * HID + k], __half2float(__ushort_as_half(hr[k])), a);
        zb[uu * MB + m] = fmaxf(a, 0.f);
    }
    __syncthreads();
    if (t < MB) {
        float a = b2[0];
        #pragma unroll 10
        for (int j = 0; j < HID; ++j)
            a = fmaf(W2[j], zb[j * MB + t], a);
        out[row0 + t] = a;
    }
}

extern "C" void kernel_launch(void* const* d_in, const int* in_sizes, int n_in,
                              void* d_out, int out_size, void* d_ws, size_t ws_size,
                              hipStream_t stream) {
    const int*   x     = (const int*)  d_in[0];
    const float* embed = (const float*)d_in[1];
    const float* W_ih  = (const float*)d_in[2];
    const float* W_hh  = (const float*)d_in[3];
    const float* b_ih  = (const float*)d_in[4];
    const float* b_hh  = (const float*)d_in[5];
    const float* W1    = (const float*)d_in[6];
    const float* b1    = (const float*)d_in[7];
    const float* W2    = (const float*)d_in[8];
    const float* b2    = (const float*)d_in[9];
    float* out = (float*)d_out;

    ushort* Bm = (ushort*)d_ws;   // 256*64*2 = 32768 B scratch

    build_B<<<(256 * KP + 255) / 256, 256, 0, stream>>>(
        embed, W_ih, W_hh, b_ih, b_hh, Bm);

    lstm4w<<<NBLK, NTHR, 0, stream>>>(
        x, Bm, W1, b1, W2, b2, out);
}

// Round 10
// 695.936 us; speedup vs baseline: 1.1155x; 1.1155x over previous
//
#include <hip/hip_runtime.h>
#include <hip/hip_fp16.h>

#define T_SEQ 2048
#define HID   50
#define KP    64      // k: 0..49 = h, 50..62 = onehot, 63 = bias
#define MB    4       // batch rows per block
#define NBLK  512     // 2048 / MB -> 2 blocks/CU
#define NTHR  256     // 4 waves
#define HSTR  80      // ushorts per h row (160 B); slots 64..77 = pad-unit dump zone
#define BUFB  (MB*HSTR)

#define NLOG2E  1.4426950408889634f   // gates scaled by -log2e (g-gate by -2log2e) in B
#define N2LOG2E 2.8853900817779268f

typedef __attribute__((ext_vector_type(8))) _Float16 half8;
typedef __attribute__((ext_vector_type(4))) float    f32x4;

__device__ __forceinline__ ushort f16b(float f){ return __half_as_ushort(__float2half(f)); }
__device__ __forceinline__ float rcp_(float x){ return __builtin_amdgcn_rcpf(x); }
__device__ __forceinline__ float ex2_(float x){ return __builtin_amdgcn_exp2f(x); }

// Bm[256 cols][64 k] f16.  col = w*64 + g*16 + c16 encodes unit u = w*16+c16, gate g
// (g: 0=i,1=f,2=g,3=o).  Row r = g*50+u.  Entries pre-scaled by -log2e (g-gate by
// -2log2e) so the MFMA emits gates in exp2 domain:
//   k<50: s*W_hh[r][k];  k in 50..62: s*embed[k-50]·W_ih[r];  k==63: s*(b_ih+b_hh)[r].
__global__ void build_B(const float* __restrict__ embed, const float* __restrict__ Wih,
                        const float* __restrict__ Whh, const float* __restrict__ bih,
                        const float* __restrict__ bhh, ushort* __restrict__ Bm) {
    int idx = blockIdx.x * blockDim.x + threadIdx.x;
    if (idx >= 256 * KP) return;
    int col = idx >> 6, k = idx & 63;
    int wq = col >> 6, g = (col >> 4) & 3, cc = col & 15;
    int u = wq * 16 + cc;
    ushort v = 0;
    if (u < HID) {
        int r = g * HID + u;
        float s = (g == 2) ? -N2LOG2E : -NLOG2E;
        if (k < HID) {
            v = f16b(s * Whh[r * HID + k]);
        } else if (k < 63) {
            float t = 0.f;
            for (int e = 0; e < HID; ++e)
                t = fmaf(embed[(k - 50) * HID + e], Wih[r * HID + e], t);
            v = f16b(s * t);
        } else {
            v = f16b(s * (bih[r] + bhh[r]));
        }
    }
    Bm[idx] = v;
}

// MB=4, 4 waves, 2 blocks/CU — the chain-minimal structure (R5). This round: chain
// shaves only. Token LDS writes at step head (drain under MFMA/act); branchless h
// write via dump zone; f-gate MFMA first so the cs-critical act starts earliest.
__global__ __launch_bounds__(NTHR, 2) void lstm4(
    const int*    __restrict__ x,
    const ushort* __restrict__ Bm,
    const float*  __restrict__ W1,
    const float*  __restrict__ b1,
    const float*  __restrict__ W2,
    const float*  __restrict__ b2,
    float*        __restrict__ out)
{
    const int t    = threadIdx.x;
    const int w    = t >> 6;
    const int l    = t & 63;
    const int q    = l >> 4;
    const int c16  = l & 15;
    const int u    = w * 16 + c16;                   // unit handled by this lane (row q)
    const int upos = (u < HID) ? u : (64 + u - HID); // pad units -> dump slots 64..77
    const int wu   = __builtin_amdgcn_readfirstlane(w);

    __shared__ __align__(16) ushort hbuf[2 * BUFB];   // 1280 B
    __shared__ float zb[HID * MB];

    // B fragments: wave w owns tiles 4w..4w+3 (gate j), col c16
    half8 bf[4][2];
    {
        const ushort* bp = Bm + (w * 64 + c16) * KP + q * 8;
        #pragma unroll
        for (int j = 0; j < 4; ++j) {
            bf[j][0] = *(const half8*)(bp + j * 16 * KP);
            bf[j][1] = *(const half8*)(bp + j * 16 * KP + 32);
        }
    }
    #pragma unroll
    for (int j = 0; j < 4; ++j)
        asm volatile("" : "+v"(bf[j][0]), "+v"(bf[j][1]));

    for (int i = t; i < 2 * BUFB; i += NTHR) hbuf[i] = 0;

    const int  row0 = blockIdx.x * MB;
    const int* xrow = x + (long)row0 * T_SEQ + (long)wu * T_SEQ;  // uniform -> s_load
    __syncthreads();
    int tk0 = xrow[0];
    int tk1 = xrow[1];
    if (l == 0) {
        hbuf[0 * BUFB + wu * HSTR + 63] = 0x3C00;        // bias slot = 1.0
        hbuf[1 * BUFB + wu * HSTR + 63] = 0x3C00;
        hbuf[0 * BUFB + wu * HSTR + 50 + tk0] = 0x3C00;  // onehot step 0
        hbuf[1 * BUFB + wu * HSTR + 50 + tk1] = 0x3C00;  // onehot step 1
    }
    int t0r = tk1, t1r = tk0, t2r = tk1;   // clear(t-1)/set(t+1) window (SGPR)
    __syncthreads();

    // Anti-phase: co-resident blocks sit in wave slots 0/1 per SIMD; delay slot-1 once.
    {
        uint slot = __builtin_amdgcn_s_getreg(6148) & 0xF;  // HW_ID.WAVE_ID[3:0]
        if (slot & 1) __builtin_amdgcn_s_sleep(6);
    }

    // A row m = h[m>>2]: quadrant lanes 4-lane-broadcast, 2-way banks = free
    const ushort* ar  = hbuf + (c16 >> 2) * HSTR + q * 8;
    ushort*       wr_ = hbuf + q * HSTR + upos;         // h write: row q (branchless)
    ushort*       hbw = hbuf + wu * HSTR + 50;          // token window base (uniform)

    float cs = 0.f;                        // cs = -2*log2e * c  (pre-scaled domain)

#define MFMA_(A,B,C) __builtin_amdgcn_mfma_f32_16x16x32_f16((A),(B),(C),0,0,0)
#define STEP(P) do {                                                              \
        int it = step + 2 + (P); if (it > T_SEQ - 1) it = T_SEQ - 1;              \
        int tknf = xrow[it];                   /* uniform s_load prefetch */      \
        half8 a0 = *(const half8*)(ar + (P) * BUFB);                              \
        half8 a1 = *(const half8*)(ar + (P) * BUFB + 32);                         \
        if (l == 0) {                          /* token writes: head of step, */  \
            ushort* hb = hbw + (1 - (P)) * BUFB;   /* drain under MFMA/act   */   \
            hb[t0r] = 0;                                                          \
            hb[t2r] = 0x3C00;                                                     \
        }                                                                         \
        t0r = t1r; t1r = t2r; t2r = tknf;                                         \
        const f32x4 zz = {0.f, 0.f, 0.f, 0.f};                                    \
        __builtin_amdgcn_s_setprio(1);                                            \
        f32x4 z1 = MFMA_(a0, bf[1][0], zz);    /* f-gate first: cs path */        \
        z1 = MFMA_(a1, bf[1][1], z1);                                             \
        f32x4 z0 = MFMA_(a0, bf[0][0], zz);    /* i */                            \
        z0 = MFMA_(a1, bf[0][1], z0);                                             \
        f32x4 z2 = MFMA_(a0, bf[2][0], zz);    /* g */                            \
        z2 = MFMA_(a1, bf[2][1], z2);                                             \
        f32x4 z3 = MFMA_(a0, bf[3][0], zz);    /* o last: off-chain until ivB */  \
        z3 = MFMA_(a1, bf[3][1], z3);                                             \
        __builtin_amdgcn_s_setprio(0);                                            \
        /* gates arrive exp2-scaled; bounded (<=~40) so no input clamps */        \
        float pf = ex2_(z1[0]);                                                   \
        float pi = ex2_(z0[0]);                                                   \
        float qg = ex2_(z2[0]);                                                   \
        float po = ex2_(z3[0]);                                                   \
        float Df = 1.f + pf;                                                      \
        float D2 = (1.f + pi) * (1.f + qg);                                       \
        float ivA = rcp_(Df * D2);                                                \
        float fv  = ivA * D2;                  /* sigm(gf) */                     \
        float igs = ivA * Df * fmaf(N2LOG2E, qg, -N2LOG2E); /* -2log2e*i*g */     \
        cs = fmaf(fv, cs, igs);                                                   \
        float qc = ex2_(fminf(cs, 30.f));      /* e^-2c = 2^cs; cs accumulates */ \
        float ivB = rcp_((1.f + po) * (1.f + qc));                                \
        float hh  = ivB * (1.f - qc);          /* sigm(go)*tanh(c) */             \
        wr_[(1 - (P)) * BUFB] = f16b(hh);      /* branchless: pads -> dump */     \
        __syncthreads();                                                          \
    } while (0)

    #pragma unroll 1
    for (int step = 0; step < T_SEQ; step += 2) {
        STEP(0);
        STEP(1);
    }
#undef STEP
#undef MFMA_

    // Epilogue MLP: final h in buffer 0 (last step wrote it), already synced.
    if (t < MB * HID) {
        int m = t & 3, uu = t >> 2;
        float a = b1[uu];
        const ushort* hr = hbuf + m * HSTR;
        #pragma unroll 10
        for (int k = 0; k < HID; ++k)
            a = fmaf(W1[uu * HID + k], __half2float(__ushort_as_half(hr[k])), a);
        zb[uu * MB + m] = fmaxf(a, 0.f);
    }
    __syncthreads();
    if (t < MB) {
        float a = b2[0];
        #pragma unroll 10
        for (int j = 0; j < HID; ++j)
            a = fmaf(W2[j], zb[j * MB + t], a);
        out[row0 + t] = a;
    }
}

extern "C" void kernel_launch(void* const* d_in, const int* in_sizes, int n_in,
                              void* d_out, int out_size, void* d_ws, size_t ws_size,
                              hipStream_t stream) {
    const int*   x     = (const int*)  d_in[0];
    const float* embed = (const float*)d_in[1];
    const float* W_ih  = (const float*)d_in[2];
    const float* W_hh  = (const float*)d_in[3];
    const float* b_ih  = (const float*)d_in[4];
    const float* b_hh  = (const float*)d_in[5];
    const float* W1    = (const float*)d_in[6];
    const float* b1    = (const float*)d_in[7];
    const float* W2    = (const float*)d_in[8];
    const float* b2    = (const float*)d_in[9];
    float* out = (float*)d_out;

    ushort* Bm = (ushort*)d_ws;   // 256*64*2 = 32768 B scratch

    build_B<<<(256 * KP + 255) / 256, 256, 0, stream>>>(
        embed, W_ih, W_hh, b_ih, b_hh, Bm);

    lstm4<<<NBLK, NTHR, 0, stream>>>(
        x, Bm, W1, b1, W2, b2, out);
}